// Round 3
// baseline (178.918 us; speedup 1.0000x reference)
//
#include <hip/hip_runtime.h>
#include <hip/hip_bf16.h>

typedef __hip_bfloat16 bf16;
typedef __fp16 half2_t __attribute__((ext_vector_type(2)));
typedef float floatx2 __attribute__((ext_vector_type(2)));
typedef _Float16 f16x8_t __attribute__((ext_vector_type(8)));
typedef float f32x4_t __attribute__((ext_vector_type(4)));

#define N_NODES 20000
#define N_EDGES 320000
#define CSTF 1e-5f

#if defined(__has_builtin)
#if __has_builtin(__builtin_amdgcn_cvt_pk_fp8_f32) && __has_builtin(__builtin_amdgcn_cvt_pk_f32_fp8)
#define M1FP8 1
#endif
#if __has_builtin(__builtin_amdgcn_fdot2)
#define HAVE_FDOT2 1
#endif
#endif

__device__ __forceinline__ half2_t u2h(unsigned int u) {
    union { unsigned int u; half2_t h; } c; c.u = u; return c.h;
}
__device__ __forceinline__ unsigned int pkh(float a, float b) {
    union { __fp16 h[2]; unsigned int u; } c;
    c.h[0] = (__fp16)a; c.h[1] = (__fp16)b;
    return c.u;
}
__device__ __forceinline__ float fdot2(half2_t a, half2_t b, float c) {
#ifdef HAVE_FDOT2
    return __builtin_amdgcn_fdot2(a, b, c, false);
#else
    return fmaf((float)a.x, (float)b.x, fmaf((float)a.y, (float)b.y, c));
#endif
}
__device__ __forceinline__ int rdl(int v, int lane) { return __builtin_amdgcn_readlane(v, lane); }
__device__ __forceinline__ float ldf(const void* p, int i, bool bf) {
    return bf ? __bfloat162float(((const bf16*)p)[i]) : ((const float*)p)[i];
}
__device__ __forceinline__ float bfbits(unsigned int lo16) {
    union { unsigned int u; float f; } c; c.u = lo16 << 16; return c.f;
}
// Per-wave int64-vs-int32 self-detection (see R7 notes).
__device__ __forceinline__ bool wave_is_i64(const void* ei, int e) {
    unsigned int hi = ((const unsigned int*)ei)[2 * e + 1];
    return !__any(hi != 0);
}

struct Args {
    const void *x, *ei, *Wq, *bq, *Wk, *bk, *Wv, *bv, *Wo, *bo, *hopwise, *headwise;
    void* out;
    _Float16* Qh;               // Q = 1+elu, f16
    _Float16* K0h;              // K0 SCALED by deg^-1/2 (row layout for hop1 gather)
    unsigned int* KVh;          // packed (K0s, V) f16 pair per (node,lane)
    unsigned int* M1K;          // fp8 path: per lane {w0(fp8x4), w1(fp8x4), K1 f32}, stride 3
    unsigned int* M1h;          // non-fp8 fallback: f16x8 per lane, stride 4
    _Float16* K1h;              // non-fp8 fallback K1
    int* bsrc;                  // bucketed adjacency: bsrc[n*64 + slot] = src
    float* gam;                 // [0..7]=g1(h), [8..15]=g2(h), [16]=hw0
    int *deg, *cnt;
};

// ---------------------------------------------------------------------------
// P1: bucketed CSR build (slot from the degree atomic itself) + dtype detect
__global__ __launch_bounds__(256) void k_p1(Args a) {
    const int t = threadIdx.x;
    const int e = blockIdx.x * 256 + t;
    bool i64 = wave_is_i64(a.ei, e);
    int r, c;
    if (i64) {
        r = (int)((const long long*)a.ei)[e];
        c = (int)((const long long*)a.ei)[N_EDGES + e];
    } else {
        r = ((const int*)a.ei)[e];
        c = ((const int*)a.ei)[N_EDGES + e];
    }
    int slot = atomicAdd(&a.deg[c], 1);
    if (slot < 64) a.bsrc[c * 64 + slot] = r;
    if (blockIdx.x < 64) {
        int bad = 0;
        for (int i = blockIdx.x * 256 + t; i < 40000; i += 64 * 256) {
            unsigned int w = ((const unsigned int*)a.x)[i];
            if (((w >> 7)  & 0xFFu) == 0xFFu) bad++;
            if (((w >> 23) & 0xFFu) == 0xFFu) bad++;
        }
        if (bad) atomicAdd(&a.cnt[0], bad);
    }
}

// ---------------------------------------------------------------------------
// QKV GEMM via MFMA: [64 nodes] x @ [Wq|Wk|Wv] (N=192), f16 in / f32 acc.
// A-frag (mfma_f32_16x16x32_f16): lane l holds A[l&15][(l>>4)*8 + e], e=0..7.
// B-frag: lane l holds B[(l>>4)*8 + e][l&15].
// D: lane l reg j -> D[(l>>4)*4 + j][l&15]  (m89-verified, dtype-independent).
// A staged in LDS with XOR swizzle (byte ^= (node&7)<<4) to break the
// 128B-row-stride bank conflict on ds_read_b128 (G4 / T2).
__global__ __launch_bounds__(256) void k_qkv(Args a) {
    __shared__ __align__(16) _Float16 sA[4096];    // 64 nodes x 64 k (swizzled), 8KB
    __shared__ __align__(16) _Float16 sB[12288];   // 12ct x 2kh x 64lane x 8, 24KB
    const int t = threadIdx.x;
    const bool bf = (a.cnt[0] < 16);
    const int n0 = blockIdx.x * 64;

    // hoisted headwise-softmax gammas (once per launch; p1 already wrote cnt)
    if (blockIdx.x == 0 && t < 8) {
        float e0 = 0.f, e1 = 0.f;
        for (int hh = 0; hh < 8; hh++) {
            e0 += __expf(ldf(a.headwise, hh * 2 + 0, bf));
            e1 += __expf(ldf(a.headwise, hh * 2 + 1, bf));
        }
        a.gam[t]     = ldf(a.hopwise, 1, bf) * __expf(ldf(a.headwise, t * 2 + 0, bf)) / e0;
        a.gam[8 + t] = ldf(a.hopwise, 2, bf) * __expf(ldf(a.headwise, t * 2 + 1, bf)) / e1;
        if (t == 0) a.gam[16] = ldf(a.hopwise, 0, bf);
    }

    // stage x -> f16 pairs, swizzled (vectorized pair load)
    for (int i = t; i < 2048; i += 256) {
        int node = i >> 5, kp = i & 31;
        int gn = n0 + node; if (gn >= N_NODES) gn = N_NODES - 1;
        float x0, x1;
        if (bf) {
            unsigned int u = ((const unsigned int*)a.x)[gn * 32 + kp];
            x0 = bfbits(u & 0xFFFFu); x1 = bfbits(u >> 16);
        } else {
            float2 xv = ((const float2*)a.x)[gn * 32 + kp];
            x0 = xv.x; x1 = xv.y;
        }
        int byte = (node * 128 + kp * 4) ^ ((node & 7) << 4);
        *(unsigned int*)((char*)sA + byte) = pkh(x0, x1);
    }
    // stage W -> fragment-order f16 pairs. i = g*64+c, g=kp*3+wsel (div by 3
    // is a cheap magic-mul; avoids /192 and %192).
    for (int i = t; i < 6144; i += 256) {
        int g = i >> 6, c = i & 63;
        int kp = g / 3, wsel = g - kp * 3;
        int k = kp * 2;
        const void* W = (wsel == 0) ? a.Wq : (wsel == 1) ? a.Wk : a.Wv;
        float w0 = ldf(W, k * 64 + c, bf);
        float w1 = ldf(W, (k + 1) * 64 + c, bf);
        int n = wsel * 64 + c;
        int ct = n >> 4, kh = k >> 5, kq = (k & 31) >> 3;
        int hoff = (((ct * 2 + kh) * 64 + kq * 16 + (n & 15)) << 3) + (k & 7);
        *(unsigned int*)&sB[hoff] = pkh(w0, w1);
    }
    __syncthreads();

    const int l = t & 63, w = t >> 6;   // wave w owns node-tile w (16 nodes)
    f16x8_t Afrag[2];
    {
        int node = w * 16 + (l & 15);
        int cb = node * 128 + ((l >> 4) * 16);
        int swz = (node & 7) << 4;
        Afrag[0] = *(const f16x8_t*)((const char*)sA + ((cb)      ^ swz));
        Afrag[1] = *(const f16x8_t*)((const char*)sA + ((cb + 64) ^ swz));
    }
    f32x4_t acc[12];
#pragma unroll
    for (int ct = 0; ct < 12; ct++) acc[ct] = (f32x4_t){0.f, 0.f, 0.f, 0.f};
#pragma unroll
    for (int kh = 0; kh < 2; kh++) {
#pragma unroll
        for (int ct = 0; ct < 12; ct++) {
            f16x8_t B = *(const f16x8_t*)&sB[((ct * 2 + kh) * 64 + l) * 8];
            acc[ct] = __builtin_amdgcn_mfma_f32_16x16x32_f16(Afrag[kh], B, acc[ct], 0, 0, 0);
        }
    }
    // epilogue: bias + elu(+1) + di-scale for K, stores (ct 0-3:Q, 4-7:K, 8-11:V)
    const int dcol = l & 15;
    float bqv[4], bkv[4], bvv[4];
#pragma unroll
    for (int ct = 0; ct < 4; ct++) {
        bqv[ct] = ldf(a.bq, ct * 16 + dcol, bf);
        bkv[ct] = ldf(a.bk, ct * 16 + dcol, bf);
        bvv[ct] = ldf(a.bv, ct * 16 + dcol, bf);
    }
    const int rbase = n0 + w * 16 + ((l >> 4) << 2);
#pragma unroll
    for (int j = 0; j < 4; j++) {
        int gn = rbase + j;
        if (gn < N_NODES) {
            int dg = a.deg[gn];
            float di = dg > 0 ? rsqrtf((float)dg) : 0.0f;
#pragma unroll
            for (int ct = 0; ct < 4; ct++) {
                float q = acc[ct][j] + bqv[ct];
                a.Qh[gn * 64 + ct * 16 + dcol] = (_Float16)(q > 0.f ? q + 1.f : __expf(q));
                float kx = acc[4 + ct][j] + bkv[ct];
                float ke = kx > 0.f ? kx + 1.f : __expf(kx);
                float k0s = di * ke;
                float vv = acc[8 + ct][j] + bvv[ct];
                a.K0h[gn * 64 + ct * 16 + dcol] = (_Float16)k0s;
                a.KVh[gn * 64 + ct * 16 + dcol] = pkh(k0s, vv);
            }
        }
    }
}

// ---------------------------------------------------------------------------
// Hop 1. One node per wave, 128-thr blocks. Lane l = (h = l>>3, j = l&7).
//   A1 = sum_src K0s[src] (x) V[src];  M1s = A1/deg;  K1s = (sum K0s)/deg.
// Per edge: 2 VMEM (K0 row uint4 + packed KV uint). Packed M1K store (fp8).
__global__ __launch_bounds__(128) void k_hop1(Args a) {
    const int l = threadIdx.x & 63;
    const int n = blockIdx.x * 2 + (threadIdx.x >> 6);
    const int hb = l & 56;
    float acc[8] = {0, 0, 0, 0, 0, 0, 0, 0};
    float kacc = 0.0f;
    const int dg = a.deg[n];
    const int m = min(dg, 64);
    if (m > 0) {
        const int srcv = a.bsrc[n * 64 + (l < m ? l : m - 1)];
#define H1_BODY(KU, KVU)                                                   \
    {                                                                      \
        half2_t p0 = u2h(KU.x), p1 = u2h(KU.y), p2 = u2h(KU.z), p3 = u2h(KU.w); \
        half2_t kv = u2h(KVU);                                             \
        float vv = (float)kv.y;                                            \
        acc[0] = fmaf(vv, (float)p0.x, acc[0]); acc[1] = fmaf(vv, (float)p0.y, acc[1]); \
        acc[2] = fmaf(vv, (float)p1.x, acc[2]); acc[3] = fmaf(vv, (float)p1.y, acc[3]); \
        acc[4] = fmaf(vv, (float)p2.x, acc[4]); acc[5] = fmaf(vv, (float)p2.y, acc[5]); \
        acc[6] = fmaf(vv, (float)p3.x, acc[6]); acc[7] = fmaf(vv, (float)p3.y, acc[7]); \
        kacc += (float)kv.x;                                               \
    }
        int e = 0;
        for (; e + 4 <= m; e += 4) {
            int sA = rdl(srcv, e), sB = rdl(srcv, e + 1), sC = rdl(srcv, e + 2), sD = rdl(srcv, e + 3);
            uint4 kA = *(const uint4*)(a.K0h + sA * 64 + hb);
            uint4 kB = *(const uint4*)(a.K0h + sB * 64 + hb);
            uint4 kC = *(const uint4*)(a.K0h + sC * 64 + hb);
            uint4 kD = *(const uint4*)(a.K0h + sD * 64 + hb);
            unsigned int vA = a.KVh[sA * 64 + l], vB = a.KVh[sB * 64 + l];
            unsigned int vC = a.KVh[sC * 64 + l], vD = a.KVh[sD * 64 + l];
            H1_BODY(kA, vA)
            H1_BODY(kB, vB)
            H1_BODY(kC, vC)
            H1_BODY(kD, vD)
        }
        for (; e < m; e++) {
            int sA = rdl(srcv, e);
            uint4 kA = *(const uint4*)(a.K0h + sA * 64 + hb);
            unsigned int vA = a.KVh[sA * 64 + l];
            H1_BODY(kA, vA)
        }
#undef H1_BODY
        float inv = 1.0f / (float)dg;
#pragma unroll
        for (int i = 0; i < 8; i++) acc[i] *= inv;
        kacc *= inv;
    }
#ifdef M1FP8
    unsigned int w0 = 0, w1 = 0;
    w0 = __builtin_amdgcn_cvt_pk_fp8_f32(acc[0], acc[1], w0, false);
    w0 = __builtin_amdgcn_cvt_pk_fp8_f32(acc[2], acc[3], w0, true);
    w1 = __builtin_amdgcn_cvt_pk_fp8_f32(acc[4], acc[5], w1, false);
    w1 = __builtin_amdgcn_cvt_pk_fp8_f32(acc[6], acc[7], w1, true);
    uint3 o3;
    o3.x = w0; o3.y = w1; o3.z = __float_as_uint(kacc);
    *(uint3*)(a.M1K + (size_t)n * 192 + l * 3) = o3;
#else
    uint4 o;
    o.x = pkh(acc[0], acc[1]); o.y = pkh(acc[2], acc[3]);
    o.z = pkh(acc[4], acc[5]); o.w = pkh(acc[6], acc[7]);
    *(uint4*)(a.M1h + (size_t)n * 256 + l * 4) = o;
    a.K1h[n * 64 + l] = (_Float16)kacc;
#endif
}

// ---------------------------------------------------------------------------
// Hop 2 + fused Wo projection. 256-thr blocks = 4 waves = 4 nodes (halves the
// barrier straggler inflation vs 8-wave blocks). fp8 path: ONE uint3 load per
// edge (M1 fp8x8 + K1 f32 packed). hidden dropped into a swizzled 16x64 f16
// LDS tile (rows 4-15 garbage; MFMA D-rows are row-independent, only rows
// 0-3 stored). Each wave then does one 16-col tile of hidden @ Wo.
__global__ __launch_bounds__(256, 4) void k_hop2o(Args a) {
    __shared__ __align__(16) _Float16 sH[1024];    // 16 rows x 64 (swizzled), 2KB
    __shared__ __align__(16) _Float16 sWo[4096];   // 4ct x 2kh x 64lane x 8, 8KB
    const int t = threadIdx.x;
    const bool bf = (a.cnt[0] < 16);
    const int l = t & 63;
    const int wv = t >> 6;                 // wave id 0..3 == local node row
    const int n = blockIdx.x * 4 + wv;
    const int hb = l & 56, h = l >> 3;

    // stage Wo fragments (consumed after the sync below)
    for (int i = t; i < 2048; i += 256) {
        int kp = i >> 6, c = i & 63;
        int k = kp * 2;
        float w0 = ldf(a.Wo, k * 64 + c, bf);
        float w1 = ldf(a.Wo, (k + 1) * 64 + c, bf);
        int ct = c >> 4, kh = k >> 5, kq = (k & 31) >> 3;
        int hoff = (((ct * 2 + kh) * 64 + kq * 16 + (c & 15)) << 3) + (k & 7);
        *(unsigned int*)&sWo[hoff] = pkh(w0, w1);
    }

    // Q row as f16x8 + own scalar
    const uint4 qrow = *(const uint4*)(a.Qh + n * 64 + hb);
    const half2_t q01 = u2h(qrow.x), q23 = u2h(qrow.y), q45 = u2h(qrow.z), q67 = u2h(qrow.w);
    const float qown = (float)a.Qh[n * 64 + l];
    float hacc = 0.0f, sk = 0.0f;
    const int dg = a.deg[n];
    const int m = min(dg, 64);
#ifdef M1FP8
    const float qf0 = (float)q01.x, qf1 = (float)q01.y, qf2 = (float)q23.x, qf3 = (float)q23.y;
    const float qf4 = (float)q45.x, qf5 = (float)q45.y, qf6 = (float)q67.x, qf7 = (float)q67.y;
#define H2_DOT(MX, MY, DST)                                                \
    {                                                                      \
        floatx2 a0 = __builtin_amdgcn_cvt_pk_f32_fp8(MX, false);           \
        floatx2 a1 = __builtin_amdgcn_cvt_pk_f32_fp8(MX, true);            \
        floatx2 a2 = __builtin_amdgcn_cvt_pk_f32_fp8(MY, false);           \
        floatx2 a3 = __builtin_amdgcn_cvt_pk_f32_fp8(MY, true);            \
        DST = qf0 * a0.x;                                                  \
        DST = fmaf(qf1, a0.y, DST); DST = fmaf(qf2, a1.x, DST);            \
        DST = fmaf(qf3, a1.y, DST); DST = fmaf(qf4, a2.x, DST);            \
        DST = fmaf(qf5, a2.y, DST); DST = fmaf(qf6, a3.x, DST);            \
        DST = fmaf(qf7, a3.y, DST);                                        \
    }
    if (m > 0) {
        const int srcv = a.bsrc[n * 64 + (l < m ? l : m - 1)];
        int e = 0;
        for (; e + 8 <= m; e += 8) {
            int s_[8];
            uint3 r_[8];
#pragma unroll
            for (int u = 0; u < 8; u++) s_[u] = rdl(srcv, e + u);
#pragma unroll
            for (int u = 0; u < 8; u++) r_[u] = *(const uint3*)(a.M1K + (size_t)s_[u] * 192 + l * 3);
#pragma unroll
            for (int u = 0; u < 8; u++) {
                float d;
                H2_DOT(r_[u].x, r_[u].y, d)
                hacc += d;
                sk += __uint_as_float(r_[u].z);
            }
        }
        for (; e < m; e++) {
            int sA = rdl(srcv, e);
            uint3 rA = *(const uint3*)(a.M1K + (size_t)sA * 192 + l * 3);
            float d;
            H2_DOT(rA.x, rA.y, d)
            hacc += d;
            sk += __uint_as_float(rA.z);
        }
    }
    const uint3 mo = *(const uint3*)(a.M1K + (size_t)n * 192 + l * 3);
    float h1r;
    H2_DOT(mo.x, mo.y, h1r)
    const float ownK1 = __uint_as_float(mo.z);
#undef H2_DOT
#else
#define H2_DOT(MU, DST)                                                    \
    {                                                                      \
        DST = fdot2(q01, u2h(MU.x), 0.0f);                                 \
        DST = fdot2(q23, u2h(MU.y), DST);                                  \
        DST = fdot2(q45, u2h(MU.z), DST);                                  \
        DST = fdot2(q67, u2h(MU.w), DST);                                  \
    }
    if (m > 0) {
        const int srcv = a.bsrc[n * 64 + (l < m ? l : m - 1)];
        int e = 0;
        for (; e + 8 <= m; e += 8) {
            int s_[8];
            uint4 m_[8];
            __fp16 k_[8];
#pragma unroll
            for (int u = 0; u < 8; u++) s_[u] = rdl(srcv, e + u);
#pragma unroll
            for (int u = 0; u < 8; u++) m_[u] = *(const uint4*)(a.M1h + (size_t)s_[u] * 256 + l * 4);
#pragma unroll
            for (int u = 0; u < 8; u++) k_[u] = a.K1h[s_[u] * 64 + l];
#pragma unroll
            for (int u = 0; u < 8; u++) {
                float d;
                H2_DOT(m_[u], d)
                hacc += d;
                sk += (float)k_[u];
            }
        }
        for (; e < m; e++) {
            int sA = rdl(srcv, e);
            uint4 mA = *(const uint4*)(a.M1h + (size_t)sA * 256 + l * 4);
            __fp16 kA = a.K1h[sA * 64 + l];
            float d;
            H2_DOT(mA, d)
            hacc += d;
            sk += (float)kA;
        }
    }
    const uint4 mo = *(const uint4*)(a.M1h + (size_t)n * 256 + l * 4);
    float h1r;
    H2_DOT(mo, h1r)
    const float ownK1 = (float)a.K1h[n * 64 + l];
#undef H2_DOT
#endif
    const float din = dg > 0 ? rsqrtf((float)dg) : 0.0f;
    const float sq  = dg > 0 ? sqrtf((float)dg)  : 0.0f;
    float h1 = h1r * sq;
    float c1 = qown * ownK1;
    float c2 = qown * sk;
#pragma unroll
    for (int dd = 1; dd < 8; dd <<= 1) {
        c1 += __shfl_xor(c1, dd);
        c2 += __shfl_xor(c2, dd);
    }
    c1 *= sq;
    c2 *= din;
    float H2v = hacc * din;

    const float vown = (float)u2h(a.KVh[n * 64 + l]).y;
    float hidden = a.gam[16] * vown
                 + a.gam[h] * h1 / (c1 + CSTF)
                 + a.gam[8 + h] * H2v / (c2 + CSTF);

    // drop into swizzled A-tile row wv
    {
        int byte = (wv * 128 + l * 2) ^ ((wv & 7) << 4);
        *(_Float16*)((char*)sH + byte) = (_Float16)hidden;
    }
    __syncthreads();

    // each wave: one 16-col tile of hidden @ Wo + bo (rows 0-3 valid)
    {
        const int ct = wv;
        int row = l & 15;
        int swz = (row & 7) << 4;
        int cb = row * 128 + ((l >> 4) * 16);
        f16x8_t A0 = *(const f16x8_t*)((const char*)sH + ((cb)      ^ swz));
        f16x8_t A1 = *(const f16x8_t*)((const char*)sH + ((cb + 64) ^ swz));
        f32x4_t acc = (f32x4_t){0.f, 0.f, 0.f, 0.f};
        f16x8_t B0 = *(const f16x8_t*)&sWo[((ct * 2 + 0) * 64 + l) * 8];
        f16x8_t B1 = *(const f16x8_t*)&sWo[((ct * 2 + 1) * 64 + l) * 8];
        acc = __builtin_amdgcn_mfma_f32_16x16x32_f16(A0, B0, acc, 0, 0, 0);
        acc = __builtin_amdgcn_mfma_f32_16x16x32_f16(A1, B1, acc, 0, 0, 0);
        const int dcol = l & 15;
        const float bov = ldf(a.bo, ct * 16 + dcol, bf);
        const int rb = (l >> 4) * 4;   // output rows rb..rb+3; only rows<4 valid
        if (rb < 4) {
            const int gb = blockIdx.x * 4 + rb;
#pragma unroll
            for (int j = 0; j < 4; j++) {
                float o = acc[j] + bov;
                if (bf) ((bf16*)a.out)[(gb + j) * 64 + ct * 16 + dcol] = __float2bfloat16(o);
                else    ((float*)a.out)[(gb + j) * 64 + ct * 16 + dcol] = o;
            }
        }
    }
}

// ---------------------------------------------------------------------------
extern "C" void kernel_launch(void* const* d_in, const int* in_sizes, int n_in,
                              void* d_out, int out_size, void* d_ws, size_t ws_size,
                              hipStream_t stream) {
    char* p = (char*)d_ws;
    auto alloc = [&](size_t bytes) {
        void* r = (void*)p;
        p += (bytes + 255) & ~(size_t)255;
        return r;
    };
    Args a;
    a.x = d_in[0];  a.ei = d_in[1];
    a.Wq = d_in[3]; a.bq = d_in[4];
    a.Wk = d_in[5]; a.bk = d_in[6];
    a.Wv = d_in[7]; a.bv = d_in[8];
    a.Wo = d_in[9]; a.bo = d_in[10];
    a.hopwise = d_in[11]; a.headwise = d_in[12];
    a.out = d_out;

    a.Qh   = (_Float16*)alloc((size_t)N_NODES * 64 * 2);
    a.K0h  = (_Float16*)alloc((size_t)N_NODES * 64 * 2);
    a.KVh  = (unsigned int*)alloc((size_t)N_NODES * 64 * 4);
    a.M1K  = (unsigned int*)alloc((size_t)N_NODES * 192 * 4);
    a.M1h  = (unsigned int*)alloc((size_t)N_NODES * 256 * 4);
    a.K1h  = (_Float16*)alloc((size_t)N_NODES * 64 * 2);
    a.bsrc = (int*)alloc((size_t)N_NODES * 64 * 4);
    a.gam  = (float*)alloc(256);
    int* zz = (int*)alloc(((size_t)N_NODES + 64) * 4);
    a.deg = zz;
    a.cnt = zz + N_NODES;

    (void)hipMemsetAsync(zz, 0, ((size_t)N_NODES + 64) * 4, stream);

    const int EB = (N_EDGES + 255) / 256;    // 1250
    const int GB = (N_NODES + 63) / 64;      // 313
    k_p1<<<EB, 256, 0, stream>>>(a);
    k_qkv<<<GB, 256, 0, stream>>>(a);
    k_hop1<<<N_NODES / 2, 128, 0, stream>>>(a);
    k_hop2o<<<N_NODES / 4, 256, 0, stream>>>(a);
}

// Round 4
// 168.988 us; speedup vs baseline: 1.0588x; 1.0588x over previous
//
#include <hip/hip_runtime.h>
#include <hip/hip_bf16.h>

typedef __hip_bfloat16 bf16;
typedef __fp16 half2_t __attribute__((ext_vector_type(2)));
typedef float floatx2 __attribute__((ext_vector_type(2)));
typedef _Float16 f16x8_t __attribute__((ext_vector_type(8)));
typedef float f32x4_t __attribute__((ext_vector_type(4)));

#define N_NODES 20000
#define N_EDGES 320000
#define CSTF 1e-5f

#if defined(__has_builtin)
#if __has_builtin(__builtin_amdgcn_cvt_pk_fp8_f32) && __has_builtin(__builtin_amdgcn_cvt_pk_f32_fp8)
#define M1FP8 1
#endif
#if __has_builtin(__builtin_amdgcn_fdot2)
#define HAVE_FDOT2 1
#endif
#endif

#ifdef M1FP8
#define M1_STRIDE 128
#define M1_LANE   2
typedef uint2 m1vec;
#else
#define M1_STRIDE 256
#define M1_LANE   4
typedef uint4 m1vec;
#endif

__device__ __forceinline__ half2_t u2h(unsigned int u) {
    union { unsigned int u; half2_t h; } c; c.u = u; return c.h;
}
__device__ __forceinline__ unsigned int pkh(float a, float b) {
    union { __fp16 h[2]; unsigned int u; } c;
    c.h[0] = (__fp16)a; c.h[1] = (__fp16)b;
    return c.u;
}
__device__ __forceinline__ float fdot2(half2_t a, half2_t b, float c) {
#ifdef HAVE_FDOT2
    return __builtin_amdgcn_fdot2(a, b, c, false);
#else
    return fmaf((float)a.x, (float)b.x, fmaf((float)a.y, (float)b.y, c));
#endif
}
__device__ __forceinline__ int rdl(int v, int lane) { return __builtin_amdgcn_readlane(v, lane); }
__device__ __forceinline__ float ldf(const void* p, int i, bool bf) {
    return bf ? __bfloat162float(((const bf16*)p)[i]) : ((const float*)p)[i];
}
__device__ __forceinline__ float bfbits(unsigned int lo16) {
    union { unsigned int u; float f; } c; c.u = lo16 << 16; return c.f;
}
// Per-wave int64-vs-int32 self-detection (see R7 notes).
__device__ __forceinline__ bool wave_is_i64(const void* ei, int e) {
    unsigned int hi = ((const unsigned int*)ei)[2 * e + 1];
    return !__any(hi != 0);
}

struct Args {
    const void *x, *ei, *Wq, *bq, *Wk, *bk, *Wv, *bv, *Wo, *bo, *hopwise, *headwise;
    void* out;
    _Float16* Qh;               // Q = 1+elu, f16
    _Float16* K0h;              // K0 SCALED by deg^-1/2 (row layout for hop1 gather)
    unsigned int* KVh;          // packed (K0s, V) f16 pair per (node,lane)
    unsigned int* M1h;          // M1^s = M1 * di_n (fp8 e4m3 uint2/lane or f16 uint4/lane)
    _Float16* K1h;              // K1s, f16
    int* bsrc;                  // bucketed adjacency: bsrc[n*64 + slot] = src
    float* gam;                 // [0..7]=g1(h), [8..15]=g2(h), [16]=hw0
    int *deg, *cnt;
};

// ---------------------------------------------------------------------------
// P1: bucketed CSR build (slot from the degree atomic itself) + dtype detect
__global__ __launch_bounds__(256) void k_p1(Args a) {
    const int t = threadIdx.x;
    const int e = blockIdx.x * 256 + t;
    bool i64 = wave_is_i64(a.ei, e);
    int r, c;
    if (i64) {
        r = (int)((const long long*)a.ei)[e];
        c = (int)((const long long*)a.ei)[N_EDGES + e];
    } else {
        r = ((const int*)a.ei)[e];
        c = ((const int*)a.ei)[N_EDGES + e];
    }
    int slot = atomicAdd(&a.deg[c], 1);
    if (slot < 64) a.bsrc[c * 64 + slot] = r;
    if (blockIdx.x < 64) {
        int bad = 0;
        for (int i = blockIdx.x * 256 + t; i < 40000; i += 64 * 256) {
            unsigned int w = ((const unsigned int*)a.x)[i];
            if (((w >> 7)  & 0xFFu) == 0xFFu) bad++;
            if (((w >> 23) & 0xFFu) == 0xFFu) bad++;
        }
        if (bad) atomicAdd(&a.cnt[0], bad);
    }
}

// ---------------------------------------------------------------------------
// QKV GEMM via MFMA: [64 nodes] x @ [Wq|Wk|Wv] (N=192), f16 in / f32 acc.
// A-frag (mfma_f32_16x16x32_f16): lane l holds A[l&15][(l>>4)*8 + e], e=0..7.
// B-frag: lane l holds B[(l>>4)*8 + e][l&15].
// D: lane l reg j -> D[(l>>4)*4 + j][l&15]  (m89-verified, dtype-independent).
// A staged in LDS with XOR swizzle (byte ^= (node&7)<<4); the XOR only
// touches byte-bits 4-6, so 8B-wide staging writes stay aligned.
__global__ __launch_bounds__(256) void k_qkv(Args a) {
    __shared__ __align__(16) _Float16 sA[4096];    // 64 nodes x 64 k (swizzled), 8KB
    __shared__ __align__(16) _Float16 sB[12288];   // 12ct x 2kh x 64lane x 8, 24KB
    const int t = threadIdx.x;
    const bool bf = (a.cnt[0] < 16);
    const int n0 = blockIdx.x * 64;

    // hoisted headwise-softmax gammas (once per launch; p1 already wrote cnt)
    if (blockIdx.x == 0 && t < 8) {
        float e0 = 0.f, e1 = 0.f;
        for (int hh = 0; hh < 8; hh++) {
            e0 += __expf(ldf(a.headwise, hh * 2 + 0, bf));
            e1 += __expf(ldf(a.headwise, hh * 2 + 1, bf));
        }
        a.gam[t]     = ldf(a.hopwise, 1, bf) * __expf(ldf(a.headwise, t * 2 + 0, bf)) / e0;
        a.gam[8 + t] = ldf(a.hopwise, 2, bf) * __expf(ldf(a.headwise, t * 2 + 1, bf)) / e1;
        if (t == 0) a.gam[16] = ldf(a.hopwise, 0, bf);
    }

    // stage x -> f16 pairs, swizzled, 8B per iteration (1024 uint2 slots)
    for (int i = t; i < 1024; i += 256) {
        int node = i >> 4, kp2 = i & 15;           // kp2 = pair-of-pairs index
        int gn = n0 + node; if (gn >= N_NODES) gn = N_NODES - 1;
        unsigned int u0, u1;
        if (bf) {
            uint2 uu = ((const uint2*)a.x)[gn * 16 + kp2];
            u0 = pkh(bfbits(uu.x & 0xFFFFu), bfbits(uu.x >> 16));
            u1 = pkh(bfbits(uu.y & 0xFFFFu), bfbits(uu.y >> 16));
        } else {
            float4 xv = ((const float4*)a.x)[gn * 16 + kp2];
            u0 = pkh(xv.x, xv.y); u1 = pkh(xv.z, xv.w);
        }
        int byte = (node * 128 + kp2 * 8) ^ ((node & 7) << 4);
        uint2 o; o.x = u0; o.y = u1;
        *(uint2*)((char*)sA + byte) = o;
    }
    // stage W -> fragment-order f16 pairs. i = g*64+c, g=kp*3+wsel (div by 3
    // is a cheap magic-mul; avoids /192 and %192).
    for (int i = t; i < 6144; i += 256) {
        int g = i >> 6, c = i & 63;
        int kp = g / 3, wsel = g - kp * 3;
        int k = kp * 2;
        const void* W = (wsel == 0) ? a.Wq : (wsel == 1) ? a.Wk : a.Wv;
        float w0 = ldf(W, k * 64 + c, bf);
        float w1 = ldf(W, (k + 1) * 64 + c, bf);
        int n = wsel * 64 + c;
        int ct = n >> 4, kh = k >> 5, kq = (k & 31) >> 3;
        int hoff = (((ct * 2 + kh) * 64 + kq * 16 + (n & 15)) << 3) + (k & 7);
        *(unsigned int*)&sB[hoff] = pkh(w0, w1);
    }
    __syncthreads();

    const int l = t & 63, w = t >> 6;   // wave w owns node-tile w (16 nodes)
    f16x8_t Afrag[2];
    {
        int node = w * 16 + (l & 15);
        int cb = node * 128 + ((l >> 4) * 16);
        int swz = (node & 7) << 4;
        Afrag[0] = *(const f16x8_t*)((const char*)sA + ((cb)      ^ swz));
        Afrag[1] = *(const f16x8_t*)((const char*)sA + ((cb + 64) ^ swz));
    }
    f32x4_t acc[12];
#pragma unroll
    for (int ct = 0; ct < 12; ct++) acc[ct] = (f32x4_t){0.f, 0.f, 0.f, 0.f};
#pragma unroll
    for (int kh = 0; kh < 2; kh++) {
#pragma unroll
        for (int ct = 0; ct < 12; ct++) {
            f16x8_t B = *(const f16x8_t*)&sB[((ct * 2 + kh) * 64 + l) * 8];
            acc[ct] = __builtin_amdgcn_mfma_f32_16x16x32_f16(Afrag[kh], B, acc[ct], 0, 0, 0);
        }
    }
    // epilogue: bias + elu(+1) + di-scale for K, stores (ct 0-3:Q, 4-7:K, 8-11:V)
    const int dcol = l & 15;
    float bqv[4], bkv[4], bvv[4];
#pragma unroll
    for (int ct = 0; ct < 4; ct++) {
        bqv[ct] = ldf(a.bq, ct * 16 + dcol, bf);
        bkv[ct] = ldf(a.bk, ct * 16 + dcol, bf);
        bvv[ct] = ldf(a.bv, ct * 16 + dcol, bf);
    }
    const int rbase = n0 + w * 16 + ((l >> 4) << 2);
#pragma unroll
    for (int j = 0; j < 4; j++) {
        int gn = rbase + j;
        if (gn < N_NODES) {
            int dg = a.deg[gn];
            float di = dg > 0 ? rsqrtf((float)dg) : 0.0f;
#pragma unroll
            for (int ct = 0; ct < 4; ct++) {
                float q = acc[ct][j] + bqv[ct];
                a.Qh[gn * 64 + ct * 16 + dcol] = (_Float16)(q > 0.f ? q + 1.f : __expf(q));
                float kx = acc[4 + ct][j] + bkv[ct];
                float ke = kx > 0.f ? kx + 1.f : __expf(kx);
                float k0s = di * ke;
                float vv = acc[8 + ct][j] + bvv[ct];
                a.K0h[gn * 64 + ct * 16 + dcol] = (_Float16)k0s;
                a.KVh[gn * 64 + ct * 16 + dcol] = pkh(k0s, vv);
            }
        }
    }
}

// ---------------------------------------------------------------------------
// Hop 1. One node per wave, 128-thr blocks. Lane l = (h = l>>3, j = l&7).
//   A1 = sum_src K0s[src] (x) V[src];  M1s = A1/deg;  K1s = (sum K0s)/deg.
// Per edge: 2 VMEM (K0 row uint4 + packed KV uint). fmaf((float)h,...) forms
// fold to v_fma_mix on gfx9+.
__global__ __launch_bounds__(128) void k_hop1(Args a) {
    const int l = threadIdx.x & 63;
    const int n = blockIdx.x * 2 + (threadIdx.x >> 6);
    const int hb = l & 56;
    float acc[8] = {0, 0, 0, 0, 0, 0, 0, 0};
    float kacc = 0.0f;
    const int dg = a.deg[n];
    const int m = min(dg, 64);
    if (m > 0) {
        const int srcv = a.bsrc[n * 64 + (l < m ? l : m - 1)];
#define H1_BODY(KU, KVU)                                                   \
    {                                                                      \
        half2_t p0 = u2h(KU.x), p1 = u2h(KU.y), p2 = u2h(KU.z), p3 = u2h(KU.w); \
        half2_t kv = u2h(KVU);                                             \
        float vv = (float)kv.y;                                            \
        acc[0] = fmaf(vv, (float)p0.x, acc[0]); acc[1] = fmaf(vv, (float)p0.y, acc[1]); \
        acc[2] = fmaf(vv, (float)p1.x, acc[2]); acc[3] = fmaf(vv, (float)p1.y, acc[3]); \
        acc[4] = fmaf(vv, (float)p2.x, acc[4]); acc[5] = fmaf(vv, (float)p2.y, acc[5]); \
        acc[6] = fmaf(vv, (float)p3.x, acc[6]); acc[7] = fmaf(vv, (float)p3.y, acc[7]); \
        kacc += (float)kv.x;                                               \
    }
        int e = 0;
        for (; e + 4 <= m; e += 4) {
            int sA = rdl(srcv, e), sB = rdl(srcv, e + 1), sC = rdl(srcv, e + 2), sD = rdl(srcv, e + 3);
            uint4 kA = *(const uint4*)(a.K0h + sA * 64 + hb);
            uint4 kB = *(const uint4*)(a.K0h + sB * 64 + hb);
            uint4 kC = *(const uint4*)(a.K0h + sC * 64 + hb);
            uint4 kD = *(const uint4*)(a.K0h + sD * 64 + hb);
            unsigned int vA = a.KVh[sA * 64 + l], vB = a.KVh[sB * 64 + l];
            unsigned int vC = a.KVh[sC * 64 + l], vD = a.KVh[sD * 64 + l];
            H1_BODY(kA, vA)
            H1_BODY(kB, vB)
            H1_BODY(kC, vC)
            H1_BODY(kD, vD)
        }
        for (; e < m; e++) {
            int sA = rdl(srcv, e);
            uint4 kA = *(const uint4*)(a.K0h + sA * 64 + hb);
            unsigned int vA = a.KVh[sA * 64 + l];
            H1_BODY(kA, vA)
        }
#undef H1_BODY
        float inv = 1.0f / (float)dg;
#pragma unroll
        for (int i = 0; i < 8; i++) acc[i] *= inv;
        kacc *= inv;
    }
#ifdef M1FP8
    unsigned int w0 = 0, w1 = 0;
    w0 = __builtin_amdgcn_cvt_pk_fp8_f32(acc[0], acc[1], w0, false);
    w0 = __builtin_amdgcn_cvt_pk_fp8_f32(acc[2], acc[3], w0, true);
    w1 = __builtin_amdgcn_cvt_pk_fp8_f32(acc[4], acc[5], w1, false);
    w1 = __builtin_amdgcn_cvt_pk_fp8_f32(acc[6], acc[7], w1, true);
    uint2 o2; o2.x = w0; o2.y = w1;
    *(uint2*)(a.M1h + (size_t)n * M1_STRIDE + l * M1_LANE) = o2;
#else
    uint4 o;
    o.x = pkh(acc[0], acc[1]); o.y = pkh(acc[2], acc[3]);
    o.z = pkh(acc[4], acc[5]); o.w = pkh(acc[6], acc[7]);
    *(uint4*)(a.M1h + (size_t)n * M1_STRIDE + l * M1_LANE) = o;
#endif
    a.K1h[n * 64 + l] = (_Float16)kacc;
}

// ---------------------------------------------------------------------------
// Hop 2 + fused Wo projection. 512-thr blocks = 8 waves = 8 nodes (R1's
// known-good config). Per edge (fp8): uint2 M1 + ushort K1 — both aligned.
// hidden dropped into a swizzled 16x64 f16 LDS tile (rows 8-15 garbage;
// MFMA D-rows are row-independent, only rows 0-7 stored). Waves 0-3 each
// do one 16-col tile of hidden @ Wo.
__global__ __launch_bounds__(512, 4) void k_hop2o(Args a) {
    __shared__ __align__(16) _Float16 sH[1024];    // 16 rows x 64 (swizzled), 2KB
    __shared__ __align__(16) _Float16 sWo[4096];   // 4ct x 2kh x 64lane x 8, 8KB
    const int t = threadIdx.x;
    const bool bf = (a.cnt[0] < 16);
    const int l = t & 63;
    const int wv = t >> 6;                 // wave id 0..7 == local node row
    const int n = blockIdx.x * 8 + wv;
    const int hb = l & 56, h = l >> 3;

    // stage Wo fragments (consumed after the sync below)
    for (int i = t; i < 2048; i += 512) {
        int kp = i >> 6, c = i & 63;
        int k = kp * 2;
        float w0 = ldf(a.Wo, k * 64 + c, bf);
        float w1 = ldf(a.Wo, (k + 1) * 64 + c, bf);
        int ct = c >> 4, kh = k >> 5, kq = (k & 31) >> 3;
        int hoff = (((ct * 2 + kh) * 64 + kq * 16 + (c & 15)) << 3) + (k & 7);
        *(unsigned int*)&sWo[hoff] = pkh(w0, w1);
    }

    // Q row as f16x8 + own scalar
    const uint4 qrow = *(const uint4*)(a.Qh + n * 64 + hb);
    const half2_t q01 = u2h(qrow.x), q23 = u2h(qrow.y), q45 = u2h(qrow.z), q67 = u2h(qrow.w);
    const float qown = (float)a.Qh[n * 64 + l];
    float hacc = 0.0f, sk = 0.0f;
    const int dg = a.deg[n];
    const int m = min(dg, 64);
#ifdef M1FP8
    const float qf0 = (float)q01.x, qf1 = (float)q01.y, qf2 = (float)q23.x, qf3 = (float)q23.y;
    const float qf4 = (float)q45.x, qf5 = (float)q45.y, qf6 = (float)q67.x, qf7 = (float)q67.y;
#define H2_DOT(MU, DST)                                                    \
    {                                                                      \
        floatx2 a0 = __builtin_amdgcn_cvt_pk_f32_fp8(MU.x, false);         \
        floatx2 a1 = __builtin_amdgcn_cvt_pk_f32_fp8(MU.x, true);          \
        floatx2 a2 = __builtin_amdgcn_cvt_pk_f32_fp8(MU.y, false);         \
        floatx2 a3 = __builtin_amdgcn_cvt_pk_f32_fp8(MU.y, true);          \
        DST = qf0 * a0.x;                                                  \
        DST = fmaf(qf1, a0.y, DST); DST = fmaf(qf2, a1.x, DST);            \
        DST = fmaf(qf3, a1.y, DST); DST = fmaf(qf4, a2.x, DST);            \
        DST = fmaf(qf5, a2.y, DST); DST = fmaf(qf6, a3.x, DST);            \
        DST = fmaf(qf7, a3.y, DST);                                        \
    }
#else
#define H2_DOT(MU, DST)                                                    \
    {                                                                      \
        DST = fdot2(q01, u2h(MU.x), 0.0f);                                 \
        DST = fdot2(q23, u2h(MU.y), DST);                                  \
        DST = fdot2(q45, u2h(MU.z), DST);                                  \
        DST = fdot2(q67, u2h(MU.w), DST);                                  \
    }
#endif
    if (m > 0) {
        const int srcv = a.bsrc[n * 64 + (l < m ? l : m - 1)];
        int e = 0;
        for (; e + 8 <= m; e += 8) {
            int s_[8];
            m1vec m_[8];
            __fp16 k_[8];
#pragma unroll
            for (int u = 0; u < 8; u++) s_[u] = rdl(srcv, e + u);
#pragma unroll
            for (int u = 0; u < 8; u++) m_[u] = *(const m1vec*)(a.M1h + (size_t)s_[u] * M1_STRIDE + l * M1_LANE);
#pragma unroll
            for (int u = 0; u < 8; u++) k_[u] = a.K1h[s_[u] * 64 + l];
#pragma unroll
            for (int u = 0; u < 8; u++) {
                float d;
                H2_DOT(m_[u], d)
                hacc += d;
                sk += (float)k_[u];
            }
        }
        for (; e < m; e++) {
            int sA = rdl(srcv, e);
            m1vec mA = *(const m1vec*)(a.M1h + (size_t)sA * M1_STRIDE + l * M1_LANE);
            __fp16 kA = a.K1h[sA * 64 + l];
            float d;
            H2_DOT(mA, d)
            hacc += d;
            sk += (float)kA;
        }
    }
    // own-node H1 / C1 (un-scale M1s,K1s by sqrt(deg))
    m1vec mo = *(const m1vec*)(a.M1h + (size_t)n * M1_STRIDE + l * M1_LANE);
    float h1r;
    H2_DOT(mo, h1r)
#undef H2_DOT
    const float ownK1 = (float)a.K1h[n * 64 + l];
    const float din = dg > 0 ? rsqrtf((float)dg) : 0.0f;
    const float sq  = dg > 0 ? sqrtf((float)dg)  : 0.0f;
    float h1 = h1r * sq;
    float c1 = qown * ownK1;
    float c2 = qown * sk;
#pragma unroll
    for (int dd = 1; dd < 8; dd <<= 1) {
        c1 += __shfl_xor(c1, dd);
        c2 += __shfl_xor(c2, dd);
    }
    c1 *= sq;
    c2 *= din;
    float H2v = hacc * din;

    const float vown = (float)u2h(a.KVh[n * 64 + l]).y;
    float hidden = a.gam[16] * vown
                 + a.gam[h] * h1 / (c1 + CSTF)
                 + a.gam[8 + h] * H2v / (c2 + CSTF);

    // drop into swizzled A-tile row wv
    {
        int byte = (wv * 128 + l * 2) ^ ((wv & 7) << 4);
        *(_Float16*)((char*)sH + byte) = (_Float16)hidden;
    }
    __syncthreads();

    // waves 0-3: one 16-col tile each of hidden @ Wo + bo (rows 0-7 valid)
    if (wv < 4) {
        const int ct = wv;
        int row = l & 15;
        int swz = (row & 7) << 4;
        int cb = row * 128 + ((l >> 4) * 16);
        f16x8_t A0 = *(const f16x8_t*)((const char*)sH + ((cb)      ^ swz));
        f16x8_t A1 = *(const f16x8_t*)((const char*)sH + ((cb + 64) ^ swz));
        f32x4_t acc = (f32x4_t){0.f, 0.f, 0.f, 0.f};
        f16x8_t B0 = *(const f16x8_t*)&sWo[((ct * 2 + 0) * 64 + l) * 8];
        f16x8_t B1 = *(const f16x8_t*)&sWo[((ct * 2 + 1) * 64 + l) * 8];
        acc = __builtin_amdgcn_mfma_f32_16x16x32_f16(A0, B0, acc, 0, 0, 0);
        acc = __builtin_amdgcn_mfma_f32_16x16x32_f16(A1, B1, acc, 0, 0, 0);
        const int dcol = l & 15;
        const float bov = ldf(a.bo, ct * 16 + dcol, bf);
        const int rb = (l >> 4) * 4;   // output rows rb..rb+3; only rows<8 valid
        if (rb < 8) {
            const int gb = blockIdx.x * 8 + rb;
#pragma unroll
            for (int j = 0; j < 4; j++) {
                float o = acc[j] + bov;
                if (bf) ((bf16*)a.out)[(gb + j) * 64 + ct * 16 + dcol] = __float2bfloat16(o);
                else    ((float*)a.out)[(gb + j) * 64 + ct * 16 + dcol] = o;
            }
        }
    }
}

// ---------------------------------------------------------------------------
extern "C" void kernel_launch(void* const* d_in, const int* in_sizes, int n_in,
                              void* d_out, int out_size, void* d_ws, size_t ws_size,
                              hipStream_t stream) {
    char* p = (char*)d_ws;
    auto alloc = [&](size_t bytes) {
        void* r = (void*)p;
        p += (bytes + 255) & ~(size_t)255;
        return r;
    };
    Args a;
    a.x = d_in[0];  a.ei = d_in[1];
    a.Wq = d_in[3]; a.bq = d_in[4];
    a.Wk = d_in[5]; a.bk = d_in[6];
    a.Wv = d_in[7]; a.bv = d_in[8];
    a.Wo = d_in[9]; a.bo = d_in[10];
    a.hopwise = d_in[11]; a.headwise = d_in[12];
    a.out = d_out;

    a.Qh   = (_Float16*)alloc((size_t)N_NODES * 64 * 2);
    a.K0h  = (_Float16*)alloc((size_t)N_NODES * 64 * 2);
    a.KVh  = (unsigned int*)alloc((size_t)N_NODES * 64 * 4);
    a.M1h  = (unsigned int*)alloc((size_t)N_NODES * M1_STRIDE * 4);
    a.K1h  = (_Float16*)alloc((size_t)N_NODES * 64 * 2);
    a.bsrc = (int*)alloc((size_t)N_NODES * 64 * 4);
    a.gam  = (float*)alloc(256);
    int* zz = (int*)alloc(((size_t)N_NODES + 64) * 4);
    a.deg = zz;
    a.cnt = zz + N_NODES;

    (void)hipMemsetAsync(zz, 0, ((size_t)N_NODES + 64) * 4, stream);

    const int EB = (N_EDGES + 255) / 256;    // 1250
    const int GB = (N_NODES + 63) / 64;      // 313
    k_p1<<<EB, 256, 0, stream>>>(a);
    k_qkv<<<GB, 256, 0, stream>>>(a);
    k_hop1<<<N_NODES / 2, 128, 0, stream>>>(a);
    k_hop2o<<<N_NODES / 8, 512, 0, stream>>>(a);
}